// Round 7
// baseline (313.677 us; speedup 1.0000x reference)
//
#include <hip/hip_runtime.h>

typedef __attribute__((ext_vector_type(8))) __bf16 bf16x8;
typedef __attribute__((ext_vector_type(4))) float f32x4;
typedef __attribute__((ext_vector_type(8))) unsigned short u16x8;
typedef __attribute__((ext_vector_type(4))) unsigned short u16x4;
typedef __attribute__((ext_vector_type(2))) unsigned int u32x2;
typedef __attribute__((ext_vector_type(4))) unsigned int u32x4;

#define MFMA16(a, b, c) __builtin_amdgcn_mfma_f32_16x16x32_bf16((a), (b), (c), 0, 0, 0)
#define WAITVM(n) asm volatile("s_waitcnt vmcnt(" #n ")" ::: "memory")

__device__ __forceinline__ unsigned short f2bf(float f) {
    unsigned int u = __float_as_uint(f);
    unsigned int r = (u + 0x7FFFu + ((u >> 16) & 1u)) >> 16;
    return (unsigned short)r;
}

__device__ __forceinline__ float fexp2(float x) {
#if __has_builtin(__builtin_amdgcn_exp2f)
    return __builtin_amdgcn_exp2f(x);
#else
    return exp2f(x);
#endif
}

// gfx950 lane-swap primitives (quad-axis data movement without LDS).
__device__ __forceinline__ u32x2 plswap32(unsigned int x, unsigned int y) {
#if __has_builtin(__builtin_amdgcn_permlane32_swap)
    return __builtin_amdgcn_permlane32_swap(x, y, false, false);
#else
    asm volatile("s_nop 1\n\tv_permlane32_swap_b32 %0, %1" : "+v"(x), "+v"(y));
    u32x2 r = {x, y};
    return r;
#endif
}
__device__ __forceinline__ u32x2 plswap16(unsigned int x, unsigned int y) {
#if __has_builtin(__builtin_amdgcn_permlane16_swap)
    return __builtin_amdgcn_permlane16_swap(x, y, false, false);
#else
    asm volatile("s_nop 1\n\tv_permlane16_swap_b32 %0, %1" : "+v"(x), "+v"(y));
    u32x2 r = {x, y};
    return r;
#endif
}

// sum across the quad axis (lanes l16, l16+16, l16+32, l16+48) via permlane swaps.
__device__ __forceinline__ float quad_reduce(float v) {
    u32x2 a = plswap32(__float_as_uint(v), __float_as_uint(v));
    v = __uint_as_float(a.x) + __uint_as_float(a.y);
    u32x2 b = plswap16(__float_as_uint(v), __float_as_uint(v));
    return __uint_as_float(b.x) + __uint_as_float(b.y);
}

// ---------------- fused prep: x->bf16 convert + 4 weight transposes ----------------
__device__ __forceinline__ void transpose_tile(const float* __restrict__ in,
                                               unsigned short* __restrict__ out,
                                               int R, int C, int bx, int by) {
    __shared__ float tile[32][33];
    const int tx = threadIdx.x & 31, ty = threadIdx.x >> 5;
    const int c0 = bx * 32, r0 = by * 32;
#pragma unroll
    for (int i = 0; i < 4; ++i)
        tile[ty + i * 8][tx] = in[(size_t)(r0 + ty + i * 8) * C + c0 + tx];
    __syncthreads();
#pragma unroll
    for (int i = 0; i < 4; ++i)
        out[(size_t)(c0 + ty + i * 8) * R + r0 + tx] = f2bf(tile[tx][ty + i * 8]);
}

__global__ __launch_bounds__(256) void k_prep(const float* __restrict__ x,
                                              const float* __restrict__ Wq,
                                              const float* __restrict__ Wkvd,
                                              const float* __restrict__ Wkvu,
                                              const float* __restrict__ Wo,
                                              unsigned short* __restrict__ xb,
                                              unsigned short* __restrict__ Wcat_t,
                                              unsigned short* __restrict__ Wkvu_t,
                                              unsigned short* __restrict__ Wo_t) {
    const int i = blockIdx.x;
    if (i < 8192) {
        const int idx = i * 256 + threadIdx.x;
        const float4 v = ((const float4*)x)[idx];
        u16x4 o = { f2bf(v.x), f2bf(v.y), f2bf(v.z), f2bf(v.w) };
        ((u16x4*)xb)[idx] = o;
    } else if (i < 12288) {
        const int j = i - 8192;
        transpose_tile(Wq, Wcat_t, 2048, 2048, j & 63, j >> 6);
    } else if (i < 13312) {
        const int j = i - 12288;
        transpose_tile(Wkvd, Wcat_t + 2048 * 2048, 2048, 512, j & 15, j >> 4);
    } else if (i < 14336) {
        const int j = i - 13312;
        transpose_tile(Wkvu, Wkvu_t, 512, 2048, j & 63, j >> 6);
    } else {
        const int j = i - 14336;
        transpose_tile(Wo, Wo_t, 2048, 2048, j & 63, j >> 6);
    }
}

// ---------------- bf16 GEMM: C[M][N] = alpha * A[M][K] @ Bt[N][K]^T ----------------
// Double-buffered LDS + single barrier per BK=32 (loads in flight across compute).
// OUT_MODE: 0 = fp32 C, 1 = bf16 C, 2 = bf16 C + transposed copy Ct (per-head d-major),
// 3 = fused q/kv_down split (col<2048 -> Cv *alpha; col>=2048 -> Ct stride 512).
template <int OUT_MODE>
__global__ __launch_bounds__(256) void k_gemm_bt(const unsigned short* __restrict__ A,
                                                 const unsigned short* __restrict__ B,
                                                 void* __restrict__ Cv,
                                                 unsigned short* __restrict__ Ct,
                                                 int M, int N, int K, float alpha) {
    __shared__ alignas(16) unsigned short As[2 * 128 * 32];
    __shared__ alignas(16) unsigned short Bs[2 * 128 * 32];
    const int tid = threadIdx.x;
    const int wave = tid >> 6;
    const int lane = tid & 63;
    const int l16 = lane & 15;
    const int quad = lane >> 4;
    const int bm = blockIdx.x * 128;  // M on x: same-XCD blocks share A-panels
    const int bn = blockIdx.y * 128;
    const int wm = (wave >> 1) * 64;
    const int wn = (wave & 1) * 64;

    const f32x4 fzero = {0.f, 0.f, 0.f, 0.f};
    f32x4 acc[4][4];
#pragma unroll
    for (int i = 0; i < 4; ++i)
#pragma unroll
        for (int j = 0; j < 4; ++j) acc[i][j] = fzero;

    auto AsL = (__attribute__((address_space(3))) unsigned short*)As;
    auto BsL = (__attribute__((address_space(3))) unsigned short*)Bs;

    const int c0 = wave * 128 + lane;

    auto stage = [&](int kt32) {
        const int boff = (kt32 & 1) * (128 * 32);
        const int kt = kt32 * 32;
#pragma unroll
        for (int j = 0; j < 2; ++j) {
            const int c = c0 + j * 64;
            __builtin_amdgcn_global_load_lds(
                (const __attribute__((address_space(1))) void*)(A + (size_t)(bm + (c >> 2)) * K + kt + (c & 3) * 8),
                (__attribute__((address_space(3))) void*)(AsL + boff + c * 8), 16, 0, 0);
            __builtin_amdgcn_global_load_lds(
                (const __attribute__((address_space(1))) void*)(B + (size_t)(bn + (c >> 2)) * K + kt + (c & 3) * 8),
                (__attribute__((address_space(3))) void*)(BsL + boff + c * 8), 16, 0, 0);
        }
    };

    const int nk = K >> 5;
    stage(0);
    for (int kt32 = 0; kt32 < nk; ++kt32) {
        __syncthreads();
        if (kt32 + 1 < nk) stage(kt32 + 1);
        const unsigned short* Ab = As + (kt32 & 1) * (128 * 32);
        const unsigned short* Bb = Bs + (kt32 & 1) * (128 * 32);

        bf16x8 af[4], bfr[4];
#pragma unroll
        for (int mt = 0; mt < 4; ++mt)
            af[mt] = *(const bf16x8*)(Ab + (wm + mt * 16 + l16) * 32 + quad * 8);
#pragma unroll
        for (int nt = 0; nt < 4; ++nt)
            bfr[nt] = *(const bf16x8*)(Bb + (wn + nt * 16 + l16) * 32 + quad * 8);
#pragma unroll
        for (int mt = 0; mt < 4; ++mt)
#pragma unroll
            for (int nt = 0; nt < 4; ++nt)
                acc[mt][nt] = MFMA16(af[mt], bfr[nt], acc[mt][nt]);
    }

#pragma unroll
    for (int mt = 0; mt < 4; ++mt)
#pragma unroll
        for (int nt = 0; nt < 4; ++nt) {
            const int row0 = bm + wm + mt * 16 + quad * 4;
            const int col = bn + wn + nt * 16 + l16;
            u16x4 pk;
#pragma unroll
            for (int r = 0; r < 4; ++r) {
                const float v0 = acc[mt][nt][r];
                if (OUT_MODE == 0) {
                    ((float*)Cv)[(size_t)(row0 + r) * N + col] = v0 * alpha;
                } else if (OUT_MODE == 3) {
                    if (col < 2048)
                        ((unsigned short*)Cv)[(size_t)(row0 + r) * 2048 + col] = f2bf(v0 * alpha);
                    else
                        Ct[(size_t)(row0 + r) * 512 + (col - 2048)] = f2bf(v0);
                } else {
                    const unsigned short b = f2bf(v0 * alpha);
                    ((unsigned short*)Cv)[(size_t)(row0 + r) * N + col] = b;
                    pk[r] = b;
                }
            }
            if (OUT_MODE == 2) {
                const size_t ti =
                    ((size_t)((row0 >> 11) * (N >> 7) + (col >> 7)) * 128 + (col & 127)) * 2048 +
                    (row0 & 2047);
                *(u16x4*)(Ct + ti) = pk;
            }
        }
}

// ---------------- flash attention, S^T formulation, no-max softmax ----------------
// R14: R13's att[2] pipeline (KVBLK=32, 4x16KB buffers, QK^T(kt)||PV(kt-1)||SM) with
// the sync rebuilt as T4 counted-vmcnt: raw s_barrier + "s_waitcnt vmcnt(4)" keeps
// 8 staging loads (tiles kt,kt+1) in flight ACROSS barriers; only tile kt's 4 are
// waited, and they had a full phase (~3400cyc >> 900cyc HBM) to land.
// [R13 lesson: __syncthreads drains vmcnt(0) at EVERY barrier -- 64 drains made the
//  4-deep buffer useless and doubled per-tile sync overhead (92.7us, both utils
//  DOWN). The drain, not the pipeline, was the regression.]
// Buffer liveness at phase kt: pv reads kt-1, qk reads kt, kt+1/kt+2 in flight ->
// 4 distinct with stage(kt+2) on &3 indexing (stage(kt+3) would collide w/ pv(kt-1)).
// WAR: stage(kt+2) issues only after the barrier proving all waves left phase kt-1.
// vmcnt ledger (4 loads/stage/wave): prologue 8; steady wait-4; tail 61:4, 62:4, 63:0.
// [R12/R11: issue-slot trims pinned at ~82us -- dependency/drain-bound, hence this.]
// Grid (16 qt, 32 bh) XCD-chunked; 4 waves; wave owns 32 q-rows; 2 blk/CU; LDS 64K.
// gload_lds + pre-swizzled sources; in-register P; T5 setprio; base-2 no-max SM.
// Writes output IN-PLACE over Q.
__global__ __launch_bounds__(256, 2) void k_attn(const unsigned short* __restrict__ Q,
                                                 const unsigned short* __restrict__ KV,
                                                 const unsigned short* __restrict__ KVT,
                                                 unsigned short* __restrict__ O) {
    __shared__ alignas(16) unsigned short Ks[4 * 32 * 128];   // [buf][kr][d], swizzled
    __shared__ alignas(16) unsigned short Vt[4 * 128 * 32];   // [buf][d][kr], swizzled

    const int tid = threadIdx.x;
    const int wave = tid >> 6, lane = tid & 63;
    const int l16 = lane & 15, quad = lane >> 4;
    const int l8 = l16 & 7;
    // bijective XCD-chunk swizzle: XCD k owns bh in [4k, 4k+4) -> KV slice L2-resident.
    const int lid = blockIdx.x + (blockIdx.y << 4);
    const int wid = ((lid & 7) << 6) + (lid >> 3);
    const int qt = wid & 15;
    const int bh = wid >> 4;
    const size_t tokbase = (size_t)(bh >> 4) * 2048;
    const int hcol = (bh & 15) * 128;
    const unsigned short* kvt_head = KVT + (size_t)bh * (128 * 2048);

    bf16x8 qf[2][4];
    const int qrow0 = qt * 128 + wave * 32;
#pragma unroll
    for (int nt = 0; nt < 2; ++nt) {
        const unsigned short* qp =
            Q + (tokbase + qrow0 + nt * 16 + l16) * 2048 + hcol + quad * 8;
#pragma unroll
        for (int kd = 0; kd < 4; ++kd) qf[nt][kd] = *(const bf16x8*)(qp + kd * 32);
    }

    const f32x4 fzero = {0.f, 0.f, 0.f, 0.f};
    f32x4 o_acc[8][2];  // O^T[d=dt*16+quad*4+r][q=nt*16+l16]
#pragma unroll
    for (int dt = 0; dt < 8; ++dt)
#pragma unroll
        for (int nt = 0; nt < 2; ++nt) o_acc[dt][nt] = fzero;
    float l_i[2] = {0.f, 0.f};  // per-lane partial; quad-reduced once in epilogue

    auto KsL = (__attribute__((address_space(3))) unsigned short*)Ks;
    auto VtL = (__attribute__((address_space(3))) unsigned short*)Vt;

    // staging geometry (per 256-thread round, KVBLK=32):
    //  K: 32 rows x 16 chunks = 512 slots (2/thread); slot=p*256+tid, r=slot>>4,
    //     cd=slot&15; r&7 p-invariant -> csK = (cd&8)|((cd&7)^(r&7)).
    //  V: 128 d-rows x 4 chunks = 512 slots; d=slot>>2, cv=slot&3; (d>>1)&3
    //     p-invariant -> csV = cv ^ ((d>>1)&3).   (bank-checked: reads 2-way, free)
    const int r4 = tid >> 4, cdK = tid & 15;
    const int csK = (cdK & 8) | ((cdK & 7) ^ (r4 & 7));
    const int dv = tid >> 2, cvV = tid & 3;
    const int csV = cvV ^ ((tid >> 3) & 3);
    const unsigned short* kp0 = KV + (tokbase + r4) * 2048 + hcol + csK * 8;
    const unsigned short* vp0 = kvt_head + (size_t)dv * 2048 + csV * 8;

    auto stage = [&](int kt) {
        auto Kb = KsL + (kt & 3) * (32 * 128) + tid * 8;
        auto Vb = VtL + (kt & 3) * (128 * 32) + tid * 8;
        const unsigned short* kp = kp0 + (size_t)kt * (32 * 2048);
        const unsigned short* vp = vp0 + kt * 32;
#pragma unroll
        for (int p = 0; p < 2; ++p) {
            __builtin_amdgcn_global_load_lds(
                (const __attribute__((address_space(1))) void*)(kp + p * (16 * 2048)),
                (__attribute__((address_space(3))) void*)(Kb + p * 2048), 16, 0, 0);
            __builtin_amdgcn_global_load_lds(
                (const __attribute__((address_space(1))) void*)(vp + (size_t)p * (64 * 2048)),
                (__attribute__((address_space(3))) void*)(Vb + p * 2048), 16, 0, 0);
        }
    };

    const int vsw = (quad ^ ((l16 >> 1) & 3)) * 8;  // V read chunk-slot (swizzled)

    // ---- pipeline stages as lambdas (static indices everywhere) ----
    f32x4 st[2][2];
    auto qk = [&](int kt) {
        const unsigned short* Kb = Ks + (kt & 3) * (32 * 128);
#pragma unroll
        for (int mt = 0; mt < 2; ++mt)
#pragma unroll
            for (int nt = 0; nt < 2; ++nt) st[mt][nt] = fzero;
#pragma unroll
        for (int kd = 0; kd < 4; ++kd)
#pragma unroll
            for (int mt = 0; mt < 2; ++mt) {
                const int c = kd * 4 + quad;
                const int sw = (c & 8) | ((c & 7) ^ l8);
                const bf16x8 kf = *(const bf16x8*)(Kb + (mt * 16 + l16) * 128 + sw * 8);
                st[mt][0] = MFMA16(kf, qf[0][kd], st[mt][0]);
                st[mt][1] = MFMA16(kf, qf[1][kd], st[mt][1]);
            }
    };
    auto pv = [&](int kt, bf16x8 (&pfr)[2]) {
        const unsigned short* Vb = Vt + (kt & 3) * (128 * 32);
#pragma unroll
        for (int dt = 0; dt < 8; ++dt) {
            const bf16x8 vf = *(const bf16x8*)(Vb + (dt * 16 + l16) * 32 + vsw);
            o_acc[dt][0] = MFMA16(vf, pfr[0], o_acc[dt][0]);
            o_acc[dt][1] = MFMA16(vf, pfr[1], o_acc[dt][1]);
        }
    };
    auto sm = [&](bf16x8 (&pfr)[2]) {
#pragma unroll
        for (int nt = 0; nt < 2; ++nt) {
            float p[2][4];
            float rs = 0.f;
#pragma unroll
            for (int mt = 0; mt < 2; ++mt)
#pragma unroll
                for (int r = 0; r < 4; ++r) {
                    p[mt][r] = fexp2(st[mt][nt][r]);
                    rs += p[mt][r];
                }
            l_i[nt] += rs;
            unsigned int aw0, aw1, bw0, bw1;
            asm("v_cvt_pk_bf16_f32 %0, %1, %2" : "=v"(aw0) : "v"(p[0][0]), "v"(p[0][1]));
            asm("v_cvt_pk_bf16_f32 %0, %1, %2" : "=v"(aw1) : "v"(p[0][2]), "v"(p[0][3]));
            asm("v_cvt_pk_bf16_f32 %0, %1, %2" : "=v"(bw0) : "v"(p[1][0]), "v"(p[1][1]));
            asm("v_cvt_pk_bf16_f32 %0, %1, %2" : "=v"(bw1) : "v"(p[1][2]), "v"(p[1][3]));
            const u32x2 e0 = plswap32(aw0, bw0);
            const u32x2 e1 = plswap32(aw1, bw1);
            const u32x2 f0 = plswap16(e0.x, e0.y);
            const u32x2 f1 = plswap16(e1.x, e1.y);
            const u32x4 w = {f0.x, f1.x, f0.y, f1.y};
            pfr[nt] = __builtin_bit_cast(bf16x8, w);
        }
    };

    bf16x8 pfrA[2], pfrB[2];

    // ---- prologue: tiles 0,1 in flight (8 loads/wave) ----
    stage(0);
    stage(1);

    // ---- phase 0 (peeled: no PV) ----
    WAITVM(4);                      // tile 0 landed; tile 1 stays in flight
    __builtin_amdgcn_s_barrier();
    stage(2);
    __builtin_amdgcn_s_setprio(1);
    qk(0);
    __builtin_amdgcn_s_setprio(0);
    sm(pfrA);

    // ---- main loop: phases 1..60 in odd/even pairs ----
    for (int kt2 = 1; kt2 <= 30; ++kt2) {
        const int ko = 2 * kt2 - 1;  // 1,3,...,59
        WAITVM(4);
        __builtin_amdgcn_s_barrier();
        stage(ko + 2);               // 3..61
        __builtin_amdgcn_s_setprio(1);
        qk(ko);
        pv(ko - 1, pfrA);            // prev tile's PV overlaps this tile's SM
        __builtin_amdgcn_s_setprio(0);
        sm(pfrB);

        const int ke = ko + 1;       // 2,4,...,60
        WAITVM(4);
        __builtin_amdgcn_s_barrier();
        stage(ke + 2);               // 4..62
        __builtin_amdgcn_s_setprio(1);
        qk(ke);
        pv(ke - 1, pfrB);
        __builtin_amdgcn_s_setprio(0);
        sm(pfrA);
    }

    // ---- tail phases 61, 62, 63 ----
    WAITVM(4);                      // outstanding {61,62} -> wait 61
    __builtin_amdgcn_s_barrier();
    stage(63);
    __builtin_amdgcn_s_setprio(1);
    qk(61);
    pv(60, pfrA);
    __builtin_amdgcn_s_setprio(0);
    sm(pfrB);

    WAITVM(4);                      // outstanding {62,63} -> wait 62
    __builtin_amdgcn_s_barrier();
    __builtin_amdgcn_s_setprio(1);
    qk(62);
    pv(61, pfrB);
    __builtin_amdgcn_s_setprio(0);
    sm(pfrA);

    WAITVM(0);                      // outstanding {63} -> drain
    __builtin_amdgcn_s_barrier();
    __builtin_amdgcn_s_setprio(1);
    qk(63);
    pv(62, pfrA);
    __builtin_amdgcn_s_setprio(0);
    sm(pfrB);
    pv(63, pfrB);

    // ---- epilogue: quad-reduce l, O^T[d][q] -> O[tok][d], packed b64 stores
#pragma unroll
    for (int nt = 0; nt < 2; ++nt) {
        const float inv = 1.0f / quad_reduce(l_i[nt]);
        unsigned short* dst = O + (tokbase + qrow0 + nt * 16 + l16) * 2048 + hcol;
#pragma unroll
        for (int dt = 0; dt < 8; ++dt) {
            u16x4 pk;
#pragma unroll
            for (int r = 0; r < 4; ++r) pk[r] = f2bf(o_acc[dt][nt][r] * inv);
            *(u16x4*)(dst + dt * 16 + quad * 4) = pk;
        }
    }
}

// ---------------- host launcher ----------------
extern "C" void kernel_launch(void* const* d_in, const int* in_sizes, int n_in,
                              void* d_out, int out_size, void* d_ws, size_t ws_size,
                              hipStream_t stream) {
    const float* x = (const float*)d_in[0];
    const float* W_q = (const float*)d_in[1];
    const float* W_kvd = (const float*)d_in[2];
    const float* W_kvu = (const float*)d_in[3];
    const float* W_o = (const float*)d_in[4];

    // 72 MB workspace (lifetime-packed):
    //   [0,16M)   xb (dead after fused GEMM) -> kvT
    //   [16,32M)  qb (q; attn writes output in-place here)
    //   [32,48M)  kvb
    //   [48,56M)  Wo_t
    //   [56,66M)  Wcat_t [2560][2048] (dead after fused GEMM)
    //   [66,68M)  Wkvu_t
    //   [68,72M)  lat
    char* w = (char*)d_ws;
    unsigned short* xb = (unsigned short*)(w);
    unsigned short* kvT = xb;
    unsigned short* qb = (unsigned short*)(w + (size_t)16 * 1024 * 1024);
    unsigned short* kvb = (unsigned short*)(w + (size_t)32 * 1024 * 1024);
    unsigned short* Wo_t = (unsigned short*)(w + (size_t)48 * 1024 * 1024);
    unsigned short* Wcat_t = (unsigned short*)(w + (size_t)56 * 1024 * 1024);
    unsigned short* Wkvu_t = (unsigned short*)(w + (size_t)66 * 1024 * 1024);
    unsigned short* lat = (unsigned short*)(w + (size_t)68 * 1024 * 1024);

    // fused prep: x->bf16 + all weight transposes (one dispatch)
    k_prep<<<18432, 256, 0, stream>>>(x, W_q, W_kvd, W_kvu, W_o, xb, Wcat_t, Wkvu_t, Wo_t);

    // fused: q = (x@W_q)*(scale*log2e) -> qb ; latent = x@W_kv_down -> lat
    // alpha = log2(e)/sqrt(128): attn uses exp2 directly (exp fold).
    k_gemm_bt<3><<<dim3(32, 20), 256, 0, stream>>>(xb, Wcat_t, qb, lat, 4096, 2560, 2048,
                                                   0.12751743f);
    // kv = latent @ W_kv_up  (+ per-head transposed copy kvT; xb is dead now)
    k_gemm_bt<2><<<dim3(32, 16), 256, 0, stream>>>(lat, Wkvu_t, kvb, kvT, 4096, 2048, 512,
                                                   1.0f);
    // flash attention (output in-place over qb); R14: counted-vmcnt att[2] pipeline
    k_attn<<<dim3(16, 32), 256, 0, stream>>>(qb, kvb, kvT, qb);
    // out = attn @ W_o  (fp32 output)
    k_gemm_bt<0><<<dim3(32, 16), 256, 0, stream>>>(qb, Wo_t, d_out, nullptr, 4096, 2048, 2048,
                                                   1.0f);
}

// Round 8
// 309.936 us; speedup vs baseline: 1.0121x; 1.0121x over previous
//
#include <hip/hip_runtime.h>

typedef __attribute__((ext_vector_type(8))) __bf16 bf16x8;
typedef __attribute__((ext_vector_type(4))) float f32x4;
typedef __attribute__((ext_vector_type(16))) float f32x16;
typedef __attribute__((ext_vector_type(8))) unsigned short u16x8;
typedef __attribute__((ext_vector_type(4))) unsigned short u16x4;
typedef __attribute__((ext_vector_type(2))) unsigned int u32x2;
typedef __attribute__((ext_vector_type(4))) unsigned int u32x4;

#define MFMA16(a, b, c) __builtin_amdgcn_mfma_f32_16x16x32_bf16((a), (b), (c), 0, 0, 0)
#define MFMA32(a, b, c) __builtin_amdgcn_mfma_f32_32x32x16_bf16((a), (b), (c), 0, 0, 0)

__device__ __forceinline__ unsigned short f2bf(float f) {
    unsigned int u = __float_as_uint(f);
    unsigned int r = (u + 0x7FFFu + ((u >> 16) & 1u)) >> 16;
    return (unsigned short)r;
}

__device__ __forceinline__ float fexp2(float x) {
#if __has_builtin(__builtin_amdgcn_exp2f)
    return __builtin_amdgcn_exp2f(x);
#else
    return exp2f(x);
#endif
}

// gfx950 lane-swap primitives (half-wave data movement without LDS).
__device__ __forceinline__ u32x2 plswap32(unsigned int x, unsigned int y) {
#if __has_builtin(__builtin_amdgcn_permlane32_swap)
    return __builtin_amdgcn_permlane32_swap(x, y, false, false);
#else
    asm volatile("s_nop 1\n\tv_permlane32_swap_b32 %0, %1" : "+v"(x), "+v"(y));
    u32x2 r = {x, y};
    return r;
#endif
}
__device__ __forceinline__ u32x2 plswap16(unsigned int x, unsigned int y) {
#if __has_builtin(__builtin_amdgcn_permlane16_swap)
    return __builtin_amdgcn_permlane16_swap(x, y, false, false);
#else
    asm volatile("s_nop 1\n\tv_permlane16_swap_b32 %0, %1" : "+v"(x), "+v"(y));
    u32x2 r = {x, y};
    return r;
#endif
}

// sum across the quad axis (lanes l16, l16+16, l16+32, l16+48) via permlane swaps.
__device__ __forceinline__ float quad_reduce(float v) {
    u32x2 a = plswap32(__float_as_uint(v), __float_as_uint(v));
    v = __uint_as_float(a.x) + __uint_as_float(a.y);
    u32x2 b = plswap16(__float_as_uint(v), __float_as_uint(v));
    return __uint_as_float(b.x) + __uint_as_float(b.y);
}

// ---------------- fused prep: x->bf16 convert + 4 weight transposes ----------------
__device__ __forceinline__ void transpose_tile(const float* __restrict__ in,
                                               unsigned short* __restrict__ out,
                                               int R, int C, int bx, int by) {
    __shared__ float tile[32][33];
    const int tx = threadIdx.x & 31, ty = threadIdx.x >> 5;
    const int c0 = bx * 32, r0 = by * 32;
#pragma unroll
    for (int i = 0; i < 4; ++i)
        tile[ty + i * 8][tx] = in[(size_t)(r0 + ty + i * 8) * C + c0 + tx];
    __syncthreads();
#pragma unroll
    for (int i = 0; i < 4; ++i)
        out[(size_t)(c0 + ty + i * 8) * R + r0 + tx] = f2bf(tile[tx][ty + i * 8]);
}

__global__ __launch_bounds__(256) void k_prep(const float* __restrict__ x,
                                              const float* __restrict__ Wq,
                                              const float* __restrict__ Wkvd,
                                              const float* __restrict__ Wkvu,
                                              const float* __restrict__ Wo,
                                              unsigned short* __restrict__ xb,
                                              unsigned short* __restrict__ Wcat_t,
                                              unsigned short* __restrict__ Wkvu_t,
                                              unsigned short* __restrict__ Wo_t) {
    const int i = blockIdx.x;
    if (i < 8192) {
        const int idx = i * 256 + threadIdx.x;
        const float4 v = ((const float4*)x)[idx];
        u16x4 o = { f2bf(v.x), f2bf(v.y), f2bf(v.z), f2bf(v.w) };
        ((u16x4*)xb)[idx] = o;
    } else if (i < 12288) {
        const int j = i - 8192;
        transpose_tile(Wq, Wcat_t, 2048, 2048, j & 63, j >> 6);
    } else if (i < 13312) {
        const int j = i - 12288;
        transpose_tile(Wkvd, Wcat_t + 2048 * 2048, 2048, 512, j & 15, j >> 4);
    } else if (i < 14336) {
        const int j = i - 13312;
        transpose_tile(Wkvu, Wkvu_t, 512, 2048, j & 63, j >> 6);
    } else {
        const int j = i - 14336;
        transpose_tile(Wo, Wo_t, 2048, 2048, j & 63, j >> 6);
    }
}

// ---------------- bf16 GEMM: C[M][N] = alpha * A[M][K] @ Bt[N][K]^T ----------------
// Double-buffered LDS + single barrier per BK=32 (loads in flight across compute).
// OUT_MODE: 0 = fp32 C, 1 = bf16 C, 2 = bf16 C + transposed copy Ct (per-head d-major),
// 3 = fused q/kv_down split (col<2048 -> Cv *alpha; col>=2048 -> Ct stride 512).
template <int OUT_MODE>
__global__ __launch_bounds__(256) void k_gemm_bt(const unsigned short* __restrict__ A,
                                                 const unsigned short* __restrict__ B,
                                                 void* __restrict__ Cv,
                                                 unsigned short* __restrict__ Ct,
                                                 int M, int N, int K, float alpha) {
    __shared__ alignas(16) unsigned short As[2 * 128 * 32];
    __shared__ alignas(16) unsigned short Bs[2 * 128 * 32];
    const int tid = threadIdx.x;
    const int wave = tid >> 6;
    const int lane = tid & 63;
    const int l16 = lane & 15;
    const int quad = lane >> 4;
    const int bm = blockIdx.x * 128;  // M on x: same-XCD blocks share A-panels
    const int bn = blockIdx.y * 128;
    const int wm = (wave >> 1) * 64;
    const int wn = (wave & 1) * 64;

    const f32x4 fzero = {0.f, 0.f, 0.f, 0.f};
    f32x4 acc[4][4];
#pragma unroll
    for (int i = 0; i < 4; ++i)
#pragma unroll
        for (int j = 0; j < 4; ++j) acc[i][j] = fzero;

    auto AsL = (__attribute__((address_space(3))) unsigned short*)As;
    auto BsL = (__attribute__((address_space(3))) unsigned short*)Bs;

    const int c0 = wave * 128 + lane;

    auto stage = [&](int kt32) {
        const int boff = (kt32 & 1) * (128 * 32);
        const int kt = kt32 * 32;
#pragma unroll
        for (int j = 0; j < 2; ++j) {
            const int c = c0 + j * 64;
            __builtin_amdgcn_global_load_lds(
                (const __attribute__((address_space(1))) void*)(A + (size_t)(bm + (c >> 2)) * K + kt + (c & 3) * 8),
                (__attribute__((address_space(3))) void*)(AsL + boff + c * 8), 16, 0, 0);
            __builtin_amdgcn_global_load_lds(
                (const __attribute__((address_space(1))) void*)(B + (size_t)(bn + (c >> 2)) * K + kt + (c & 3) * 8),
                (__attribute__((address_space(3))) void*)(BsL + boff + c * 8), 16, 0, 0);
        }
    };

    const int nk = K >> 5;
    stage(0);
    for (int kt32 = 0; kt32 < nk; ++kt32) {
        __syncthreads();
        if (kt32 + 1 < nk) stage(kt32 + 1);
        const unsigned short* Ab = As + (kt32 & 1) * (128 * 32);
        const unsigned short* Bb = Bs + (kt32 & 1) * (128 * 32);

        bf16x8 af[4], bfr[4];
#pragma unroll
        for (int mt = 0; mt < 4; ++mt)
            af[mt] = *(const bf16x8*)(Ab + (wm + mt * 16 + l16) * 32 + quad * 8);
#pragma unroll
        for (int nt = 0; nt < 4; ++nt)
            bfr[nt] = *(const bf16x8*)(Bb + (wn + nt * 16 + l16) * 32 + quad * 8);
#pragma unroll
        for (int mt = 0; mt < 4; ++mt)
#pragma unroll
            for (int nt = 0; nt < 4; ++nt)
                acc[mt][nt] = MFMA16(af[mt], bfr[nt], acc[mt][nt]);
    }

#pragma unroll
    for (int mt = 0; mt < 4; ++mt)
#pragma unroll
        for (int nt = 0; nt < 4; ++nt) {
            const int row0 = bm + wm + mt * 16 + quad * 4;
            const int col = bn + wn + nt * 16 + l16;
            u16x4 pk;
#pragma unroll
            for (int r = 0; r < 4; ++r) {
                const float v0 = acc[mt][nt][r];
                if (OUT_MODE == 0) {
                    ((float*)Cv)[(size_t)(row0 + r) * N + col] = v0 * alpha;
                } else if (OUT_MODE == 3) {
                    if (col < 2048)
                        ((unsigned short*)Cv)[(size_t)(row0 + r) * 2048 + col] = f2bf(v0 * alpha);
                    else
                        Ct[(size_t)(row0 + r) * 512 + (col - 2048)] = f2bf(v0);
                } else {
                    const unsigned short b = f2bf(v0 * alpha);
                    ((unsigned short*)Cv)[(size_t)(row0 + r) * N + col] = b;
                    pk[r] = b;
                }
            }
            if (OUT_MODE == 2) {
                const size_t ti =
                    ((size_t)((row0 >> 11) * (N >> 7) + (col >> 7)) * 128 + (col & 127)) * 2048 +
                    (row0 & 2047);
                *(u16x4*)(Ct + ti) = pk;
            }
        }
}

// ---------------- flash attention, S^T formulation, no-max softmax ----------------
// R15 = R12's skeleton (KVBLK=64, 2-deep dbuf, __syncthreads, gload_lds + pre-swz
// sources: best measured 81.6us) with the math moved to 32x32x16 MFMA:
//  - QK^T: st[mt] (mt=2 k-blocks of 32) over 8 K-steps; A=K (LDS), B=Q (regs).
//    C layout (m74/m101): col q = lane&31, row k = (r&3)+8*(r>>2)+4*(lane>>5).
//  - Half the MFMA instructions (32 vs 64/wave/tile) at ~15% better pipe rate
//    (m119: 2495 vs 2176 TF); LDS bytes/reads unchanged (same 32 b128/tile).
//  - P C->B repack: one plswap32(w0,w2) fills B-words {0,2}; 8 swaps/tile (was 16).
//  - l-reduce: single deferred permlane32 (partner half-wave), no quad tree.
//  - Same Ks/Vt layouts + swizzles (read chunk c=2kd+hi / 2ks+hi; per-16-lane
//    bank pattern stays 2-way == free).
// [R14/R13 lesson: sync restructures (KVBLK=32 pipeline, counted vmcnt) are net-
//  negative at 2 blk/CU; R12's 1-barrier-per-tile is the sync optimum.]
// [R11/R12 lesson: issue trims pinned at ~82us -- attacking instruction COUNT on
//  the dependency chain (this round) is the remaining in-structure lever.]
// Grid (16 qt, 32 bh) XCD-chunked; 4 waves; wave owns 32 q-rows; 2 blk/CU; LDS 64K.
// Base-2 no-max softmax (log2e folded into q). Writes output IN-PLACE over Q.
__global__ __launch_bounds__(256, 2) void k_attn(const unsigned short* __restrict__ Q,
                                                 const unsigned short* __restrict__ KV,
                                                 const unsigned short* __restrict__ KVT,
                                                 unsigned short* __restrict__ O) {
    __shared__ alignas(16) unsigned short Ks[2 * 64 * 128];   // [buf][kr][d], swizzled
    __shared__ alignas(16) unsigned short Vt[2 * 128 * 64];   // [buf][d][kr], swizzled

    const int tid = threadIdx.x;
    const int wave = tid >> 6, lane = tid & 63;
    const int q31 = lane & 31;       // this lane's q column (within wave's 32 rows)
    const int hi = lane >> 5;        // half-wave: k/d sub-block selector
    const int l8 = q31 & 7;
    // bijective XCD-chunk swizzle: XCD k owns bh in [4k, 4k+4) -> KV slice L2-resident.
    const int lid = blockIdx.x + (blockIdx.y << 4);
    const int wid = ((lid & 7) << 6) + (lid >> 3);
    const int qt = wid & 15;
    const int bh = wid >> 4;
    const size_t tokbase = (size_t)(bh >> 4) * 2048;
    const int hcol = (bh & 15) * 128;
    const unsigned short* kvt_head = KVT + (size_t)bh * (128 * 2048);

    // Q B-operand frags: lane holds Q[q31][d = kd*16 + hi*8 + 0..7], kd = 0..7
    bf16x8 qf[8];
    const int qrow0 = qt * 128 + wave * 32;
    {
        const unsigned short* qp = Q + (tokbase + qrow0 + q31) * 2048 + hcol + hi * 8;
#pragma unroll
        for (int kd = 0; kd < 8; ++kd) qf[kd] = *(const bf16x8*)(qp + kd * 16);
    }

    f32x16 o_acc[4];  // O^T 32x32 blocks: d = 32*dt + (r&3)+8*(r>>2)+4*hi, q = q31
#pragma unroll
    for (int dt = 0; dt < 4; ++dt)
#pragma unroll
        for (int r = 0; r < 16; ++r) o_acc[dt][r] = 0.f;
    float l_i = 0.f;  // per-lane partial (own half-wave k's); partner-summed at end

    auto KsL = (__attribute__((address_space(3))) unsigned short*)Ks;
    auto VtL = (__attribute__((address_space(3))) unsigned short*)Vt;

    // staging geometry (per 256-thread round, KVBLK=64) -- identical to R12:
    //  K: 16 rows x 16 chunks; source chunk preswizzled csK = (cd&8)|((cd&7)^(r&7)).
    //  V: 32 d-rows x 8 chunks; csV = cv ^ (d&7).
    const int r4 = tid >> 4, cdK = tid & 15;
    const int csK = (cdK & 8) | ((cdK & 7) ^ (r4 & 7));
    const int dv = tid >> 3, cvV = tid & 7;
    const int csV = cvV ^ (dv & 7);
    const unsigned short* kp0 = KV + (tokbase + r4) * 2048 + hcol + csK * 8;
    const unsigned short* vp0 = kvt_head + (size_t)dv * 2048 + csV * 8;

    auto stage = [&](int kt) {
        auto Kb = KsL + (kt & 1) * (64 * 128) + tid * 8;
        auto Vb = VtL + (kt & 1) * (128 * 64) + tid * 8;
        const unsigned short* kp = kp0 + (size_t)kt * (64 * 2048);
        const unsigned short* vp = vp0 + kt * 64;
#pragma unroll
        for (int p = 0; p < 4; ++p) {
            __builtin_amdgcn_global_load_lds(
                (const __attribute__((address_space(1))) void*)(kp + p * (16 * 2048)),
                (__attribute__((address_space(3))) void*)(Kb + p * 2048), 16, 0, 0);
            __builtin_amdgcn_global_load_lds(
                (const __attribute__((address_space(1))) void*)(vp + (size_t)p * (32 * 2048)),
                (__attribute__((address_space(3))) void*)(Vb + p * 2048), 16, 0, 0);
        }
    };

    stage(0);

    for (int kt = 0; kt < 32; ++kt) {
        __syncthreads();  // buf[kt&1] loads drained (vmcnt 0 before barrier)
        if (kt < 31) stage(kt + 1);  // DMA into dead buffer; in flight across compute
        const unsigned short* Kb = Ks + (kt & 1) * (64 * 128);
        const unsigned short* Vb = Vt + (kt & 1) * (128 * 64);

        // ---- S^T = K @ Q^T (32x32x16): st[mt] covers k = 32mt+0..31, q = q31.
        // A-frag: lane holds K[k = 32mt+q31][d = kd*16 + hi*8 + 0..7] -> chunk
        // c = 2kd+hi, swizzled slot sw = (c&8)|((c&7)^(k&7)); k&7 == l8.
        f32x16 st[2];
#pragma unroll
        for (int r = 0; r < 16; ++r) { st[0][r] = 0.f; st[1][r] = 0.f; }
        __builtin_amdgcn_s_setprio(1);
#pragma unroll
        for (int kd = 0; kd < 8; ++kd) {
            const int c = 2 * kd + hi;
            const int sw = (c & 8) | ((c & 7) ^ l8);
#pragma unroll
            for (int mt = 0; mt < 2; ++mt) {
                const bf16x8 kf = *(const bf16x8*)(Kb + (mt * 32 + q31) * 128 + sw * 8);
                st[mt] = MFMA32(kf, qf[kd], st[mt]);
            }
        }
        __builtin_amdgcn_s_setprio(0);

        // ---- softmax numerator p = exp2(s') and in-register P^T pack.
        // C rows (own): k = (r&3)+8*(r>>2)+4*hi (+32mt). B-frag for k-step s needs
        // k = 16s + hi*8 + 0..7: words {0,1} own, {2,3} from partner half-wave ->
        // one plswap32(w0,w2) yields B-words {0,2}; plswap32(w1,w3) yields {1,3}.
        bf16x8 pfrk[2][2];  // [mt][s]: P k-step (32mt+16s..+15), q = q31
#pragma unroll
        for (int mt = 0; mt < 2; ++mt) {
            float p[16];
            float rs = 0.f;
#pragma unroll
            for (int r = 0; r < 16; ++r) {
                p[r] = fexp2(st[mt][r]);
                rs += p[r];
            }
            l_i += rs;
#pragma unroll
            for (int s = 0; s < 2; ++s) {
                unsigned int w0, w1, w2, w3;
                asm("v_cvt_pk_bf16_f32 %0, %1, %2" : "=v"(w0) : "v"(p[s * 8 + 0]), "v"(p[s * 8 + 1]));
                asm("v_cvt_pk_bf16_f32 %0, %1, %2" : "=v"(w1) : "v"(p[s * 8 + 2]), "v"(p[s * 8 + 3]));
                asm("v_cvt_pk_bf16_f32 %0, %1, %2" : "=v"(w2) : "v"(p[s * 8 + 4]), "v"(p[s * 8 + 5]));
                asm("v_cvt_pk_bf16_f32 %0, %1, %2" : "=v"(w3) : "v"(p[s * 8 + 6]), "v"(p[s * 8 + 7]));
                const u32x2 u02 = plswap32(w0, w2);  // -> B-words 0 and 2
                const u32x2 u13 = plswap32(w1, w3);  // -> B-words 1 and 3
                const u32x4 w = {u02.x, u13.x, u02.y, u13.y};
                pfrk[mt][s] = __builtin_bit_cast(bf16x8, w);
            }
        }

        // ---- O^T += V^T @ P^T (32x32x16). A-frag: V^T[d = 32dt+q31]
        // [kr = 16ks + hi*8 + 0..7] -> Vt chunk 2ks+hi, swizzled by d&7 == l8.
        __builtin_amdgcn_s_setprio(1);
#pragma unroll
        for (int ks = 0; ks < 4; ++ks) {
            const int swv = ((2 * ks + hi) ^ l8) * 8;
            const bf16x8 pf = pfrk[ks >> 1][ks & 1];
#pragma unroll
            for (int dt = 0; dt < 4; ++dt) {
                const bf16x8 vf = *(const bf16x8*)(Vb + (dt * 32 + q31) * 64 + swv);
                o_acc[dt] = MFMA32(vf, pf, o_acc[dt]);
            }
        }
        __builtin_amdgcn_s_setprio(0);
    }

    // ---- epilogue: partner-sum l, O^T[d][q] -> O[tok][d], packed b64 stores
    {
        const u32x2 a = plswap32(__float_as_uint(l_i), __float_as_uint(l_i));
        const float inv = 1.0f / (__uint_as_float(a.x) + __uint_as_float(a.y));
        unsigned short* dst = O + (tokbase + qrow0 + q31) * 2048 + hcol + hi * 4;
#pragma unroll
        for (int dt = 0; dt < 4; ++dt)
#pragma unroll
            for (int g = 0; g < 4; ++g) {
                u16x4 pk;
#pragma unroll
                for (int j = 0; j < 4; ++j) pk[j] = f2bf(o_acc[dt][g * 4 + j] * inv);
                *(u16x4*)(dst + dt * 32 + g * 8) = pk;
            }
    }
}

// ---------------- host launcher ----------------
extern "C" void kernel_launch(void* const* d_in, const int* in_sizes, int n_in,
                              void* d_out, int out_size, void* d_ws, size_t ws_size,
                              hipStream_t stream) {
    const float* x = (const float*)d_in[0];
    const float* W_q = (const float*)d_in[1];
    const float* W_kvd = (const float*)d_in[2];
    const float* W_kvu = (const float*)d_in[3];
    const float* W_o = (const float*)d_in[4];

    // 72 MB workspace (lifetime-packed):
    //   [0,16M)   xb (dead after fused GEMM) -> kvT
    //   [16,32M)  qb (q; attn writes output in-place here)
    //   [32,48M)  kvb
    //   [48,56M)  Wo_t
    //   [56,66M)  Wcat_t [2560][2048] (dead after fused GEMM)
    //   [66,68M)  Wkvu_t
    //   [68,72M)  lat
    char* w = (char*)d_ws;
    unsigned short* xb = (unsigned short*)(w);
    unsigned short* kvT = xb;
    unsigned short* qb = (unsigned short*)(w + (size_t)16 * 1024 * 1024);
    unsigned short* kvb = (unsigned short*)(w + (size_t)32 * 1024 * 1024);
    unsigned short* Wo_t = (unsigned short*)(w + (size_t)48 * 1024 * 1024);
    unsigned short* Wcat_t = (unsigned short*)(w + (size_t)56 * 1024 * 1024);
    unsigned short* Wkvu_t = (unsigned short*)(w + (size_t)66 * 1024 * 1024);
    unsigned short* lat = (unsigned short*)(w + (size_t)68 * 1024 * 1024);

    // fused prep: x->bf16 + all weight transposes (one dispatch)
    k_prep<<<18432, 256, 0, stream>>>(x, W_q, W_kvd, W_kvu, W_o, xb, Wcat_t, Wkvu_t, Wo_t);

    // fused: q = (x@W_q)*(scale*log2e) -> qb ; latent = x@W_kv_down -> lat
    // alpha = log2(e)/sqrt(128): attn uses exp2 directly (exp fold).
    k_gemm_bt<3><<<dim3(32, 20), 256, 0, stream>>>(xb, Wcat_t, qb, lat, 4096, 2560, 2048,
                                                   0.12751743f);
    // kv = latent @ W_kv_up  (+ per-head transposed copy kvT; xb is dead now)
    k_gemm_bt<2><<<dim3(32, 16), 256, 0, stream>>>(lat, Wkvu_t, kvb, kvT, 4096, 2048, 512,
                                                   1.0f);
    // flash attention (output in-place over qb); R15: 32x32x16 MFMA on R12 skeleton
    k_attn<<<dim3(16, 32), 256, 0, stream>>>(qb, kvb, kvT, qb);
    // out = attn @ W_o  (fp32 output)
    k_gemm_bt<0><<<dim3(32, 16), 256, 0, stream>>>(qb, Wo_t, d_out, nullptr, 4096, 2048, 2048,
                                                   1.0f);
}